// Round 2
// baseline (2933.278 us; speedup 1.0000x reference)
//
#include <hip/hip_runtime.h>
#include <stdint.h>

#define N_NODES 100000
#define N_EDGES 1600000
#define D 128

typedef long long i64;

// ---------------------------------------------------------------------------
// Kernel 1: acc = x   (acc lives in d_out; float4 copy)
// ---------------------------------------------------------------------------
__global__ __launch_bounds__(256) void init_acc_kernel(
    const float* __restrict__ x, float* __restrict__ acc)
{
    const int i = blockIdx.x * blockDim.x + threadIdx.x;
    const int n = N_NODES * D / 4;
    if (i < n)
        reinterpret_cast<float4*>(acc)[i] = reinterpret_cast<const float4*>(x)[i];
}

// ---------------------------------------------------------------------------
// Kernel 2: per-edge  acc[dst] += relu(x[src] + edge_attr[e])
// 32 lanes per edge, float4 per lane (32*16B = 512B = one row), 4 f32 atomics.
// NOTE: harness delivers integer inputs as int32 (edge_index: [2, E] int32).
// ---------------------------------------------------------------------------
__global__ __launch_bounds__(256) void edge_scatter_kernel(
    const float* __restrict__ x,
    const int*  __restrict__ src,
    const int*  __restrict__ dst,
    const float* __restrict__ ea,
    float* __restrict__ acc)
{
    const int lane = threadIdx.x & 31;
    const int grp  = threadIdx.x >> 5;           // 8 edges per 256-thr block
    const i64 e = (i64)blockIdx.x * 8 + grp;
    if (e >= N_EDGES) return;

    const int s = src[e];
    const int d = dst[e];
    const int j = lane * 4;

    const float4 xv = *reinterpret_cast<const float4*>(x  + (i64)s * D + j);
    const float4 ev = *reinterpret_cast<const float4*>(ea + e * D + j);

    float4 m;
    m.x = fmaxf(xv.x + ev.x, 0.0f);
    m.y = fmaxf(xv.y + ev.y, 0.0f);
    m.z = fmaxf(xv.z + ev.z, 0.0f);
    m.w = fmaxf(xv.w + ev.w, 0.0f);

    float* p = acc + (i64)d * D + j;
    atomicAdd(p + 0, m.x);
    atomicAdd(p + 1, m.y);
    atomicAdd(p + 2, m.z);
    atomicAdd(p + 3, m.w);
}

// ---------------------------------------------------------------------------
// Kernel 3: one MLP layer, in-place safe (rows staged to LDS before write).
//   hout[i][j] = (relu?)( sum_k hin[i][k] * w[k][j] + b[j] )
// 512 threads: j = tid&127 (output column), q = tid>>7 (row quad).
// Each thread computes 4 rows per chunk -> one LDS w-read feeds 4 FMAs.
// LDS: 64KB weights + 8KB row stage -> 2 blocks/CU (160 KiB/CU), 16 waves/CU.
// ---------------------------------------------------------------------------
#define MLP_THREADS 512
#define ROWS_PER_CHUNK 16
#define CHUNKS_PER_BLOCK 4
#define ROWS_PER_BLOCK (ROWS_PER_CHUNK * CHUNKS_PER_BLOCK)   // 64

template<bool RELU>
__global__ __launch_bounds__(MLP_THREADS) void mlp_layer_kernel(
    const float* __restrict__ hin,
    const float* __restrict__ w,
    const float* __restrict__ b,
    float* __restrict__ hout)
{
    __shared__ float ws_[D * D];                  // 64 KiB
    __shared__ float bs_[D];
    __shared__ float hrow[ROWS_PER_CHUNK][D];     // 8 KiB

    const int tid = threadIdx.x;

    // stage weights (float4, coalesced)
    for (int t = tid; t < D * D / 4; t += MLP_THREADS)
        reinterpret_cast<float4*>(ws_)[t] = reinterpret_cast<const float4*>(w)[t];
    if (tid < D) bs_[tid] = b[tid];

    const int j = tid & (D - 1);
    const int q = tid >> 7;                        // 0..3
    const int rowBase = blockIdx.x * ROWS_PER_BLOCK;

    for (int c = 0; c < CHUNKS_PER_BLOCK; ++c) {
        const int chunkRow = rowBase + c * ROWS_PER_CHUNK;

        __syncthreads();   // prev chunk's hrow readers done (and weights ready)

        // stage 16 rows cooperatively (float4 per thread)
        {
            const int r   = tid >> 5;              // 0..15
            const int col = (tid & 31) * 4;
            const int gi  = chunkRow + r;
            float4 v = make_float4(0.f, 0.f, 0.f, 0.f);
            if (gi < N_NODES)
                v = *reinterpret_cast<const float4*>(hin + (i64)gi * D + col);
            *reinterpret_cast<float4*>(&hrow[r][col]) = v;
        }
        __syncthreads();

        float acc0 = bs_[j], acc1 = bs_[j], acc2 = bs_[j], acc3 = bs_[j];
        const int r0 = q * 4;
        #pragma unroll 4
        for (int k = 0; k < D; ++k) {
            const float wv = ws_[k * D + j];       // lanes j consecutive: 2-way (free)
            acc0 = fmaf(hrow[r0 + 0][k], wv, acc0); // broadcast reads
            acc1 = fmaf(hrow[r0 + 1][k], wv, acc1);
            acc2 = fmaf(hrow[r0 + 2][k], wv, acc2);
            acc3 = fmaf(hrow[r0 + 3][k], wv, acc3);
        }
        if (RELU) {
            acc0 = fmaxf(acc0, 0.f); acc1 = fmaxf(acc1, 0.f);
            acc2 = fmaxf(acc2, 0.f); acc3 = fmaxf(acc3, 0.f);
        }

        const int gi = chunkRow + r0;
        if (gi + 0 < N_NODES) hout[(i64)(gi + 0) * D + j] = acc0;
        if (gi + 1 < N_NODES) hout[(i64)(gi + 1) * D + j] = acc1;
        if (gi + 2 < N_NODES) hout[(i64)(gi + 2) * D + j] = acc2;
        if (gi + 3 < N_NODES) hout[(i64)(gi + 3) * D + j] = acc3;
    }
}

// ---------------------------------------------------------------------------
extern "C" void kernel_launch(void* const* d_in, const int* in_sizes, int n_in,
                              void* d_out, int out_size, void* d_ws, size_t ws_size,
                              hipStream_t stream)
{
    const float* x  = (const float*)d_in[0];
    const int*   ei = (const int*)  d_in[1];   // [2, E] delivered as int32
    const float* ea = (const float*)d_in[2];
    const float* w1 = (const float*)d_in[3];
    const float* b1 = (const float*)d_in[4];
    const float* w2 = (const float*)d_in[5];
    const float* b2 = (const float*)d_in[6];
    float* out = (float*)d_out;

    const int* src = ei;            // edge_index[0]
    const int* dst = ei + N_EDGES;  // edge_index[1]

    float* acc = out;               // use d_out as the aggregation buffer

    // 1) acc = x
    {
        const int n = N_NODES * D / 4;
        init_acc_kernel<<<(n + 255) / 256, 256, 0, stream>>>(x, acc);
    }

    // 2) scatter-add relu(x[src] + edge_attr)
    {
        const int blocks = (N_EDGES + 7) / 8;   // 8 edges per block
        edge_scatter_kernel<<<blocks, 256, 0, stream>>>(x, src, dst, ea, acc);
    }

    // 3) h = relu(acc @ w1 + b1)   (in-place on d_out)
    // 4) out = h @ w2 + b2         (in-place on d_out)
    {
        const int blocks = (N_NODES + ROWS_PER_BLOCK - 1) / ROWS_PER_BLOCK;
        mlp_layer_kernel<true ><<<blocks, MLP_THREADS, 0, stream>>>(acc, w1, b1, acc);
        mlp_layer_kernel<false><<<blocks, MLP_THREADS, 0, stream>>>(acc, w2, b2, out);
    }
}

// Round 3
// 683.896 us; speedup vs baseline: 4.2891x; 4.2891x over previous
//
#include <hip/hip_runtime.h>
#include <stdint.h>

#define N_NODES 100000
#define N_EDGES 1600000
#define D 128

typedef long long i64;

// ===========================================================================
// CSR-build + gather path (no f32 atomics)
// ws layout (ints): counts[N] | offsets[N+1] | cursor[N] | blockSums[128] | bucket[E]
// ===========================================================================
#define SCAN_CHUNK 1024
#define SCAN_THREADS 256
#define N_CHUNKS ((N_NODES + SCAN_CHUNK - 1) / SCAN_CHUNK)   // 98

__global__ __launch_bounds__(256) void count_zero_kernel(int* __restrict__ counts)
{
    const int i = blockIdx.x * 256 + threadIdx.x;
    if (i < N_NODES) counts[i] = 0;
}

__global__ __launch_bounds__(256) void hist_kernel(
    const int* __restrict__ dst, int* __restrict__ counts)
{
    const int e = blockIdx.x * 256 + threadIdx.x;
    if (e < N_EDGES) atomicAdd(&counts[dst[e]], 1);
}

__global__ __launch_bounds__(SCAN_THREADS) void scan_pass1(
    const int* __restrict__ counts, int* __restrict__ blockSums)
{
    __shared__ int sdata[SCAN_THREADS];
    const int b = blockIdx.x, t = threadIdx.x;
    const int base = b * SCAN_CHUNK + t * 4;
    int s = 0;
    #pragma unroll
    for (int k = 0; k < 4; ++k) {
        const int i = base + k;
        if (i < N_NODES) s += counts[i];
    }
    sdata[t] = s; __syncthreads();
    for (int off = SCAN_THREADS / 2; off > 0; off >>= 1) {
        if (t < off) sdata[t] += sdata[t + off];
        __syncthreads();
    }
    if (t == 0) blockSums[b] = sdata[0];
}

__global__ __launch_bounds__(128) void scan_pass2(
    int* __restrict__ blockSums, int* __restrict__ offsets)
{
    __shared__ int sh[128];
    const int t = threadIdx.x;
    const int v = (t < N_CHUNKS) ? blockSums[t] : 0;
    sh[t] = v; __syncthreads();
    for (int off = 1; off < 128; off <<= 1) {
        const int add = (t >= off) ? sh[t - off] : 0;
        __syncthreads();
        sh[t] += add;
        __syncthreads();
    }
    const int incl = sh[t];
    if (t < N_CHUNKS) blockSums[t] = incl - v;       // exclusive base per chunk
    if (t == N_CHUNKS - 1) offsets[N_NODES] = incl;  // total = N_EDGES
}

__global__ __launch_bounds__(SCAN_THREADS) void scan_pass3(
    const int* __restrict__ counts, const int* __restrict__ blockSums,
    int* __restrict__ offsets, int* __restrict__ cursor)
{
    __shared__ int sh[SCAN_THREADS];
    const int b = blockIdx.x, t = threadIdx.x;
    const int base = b * SCAN_CHUNK + t * 4;
    int v[4]; int s = 0;
    #pragma unroll
    for (int k = 0; k < 4; ++k) {
        const int i = base + k;
        v[k] = (i < N_NODES) ? counts[i] : 0;
        s += v[k];
    }
    sh[t] = s; __syncthreads();
    for (int off = 1; off < SCAN_THREADS; off <<= 1) {
        const int add = (t >= off) ? sh[t - off] : 0;
        __syncthreads();
        sh[t] += add;
        __syncthreads();
    }
    int run = blockSums[b] + (sh[t] - s);
    #pragma unroll
    for (int k = 0; k < 4; ++k) {
        const int i = base + k;
        if (i < N_NODES) { offsets[i] = run; cursor[i] = run; }
        run += v[k];
    }
}

__global__ __launch_bounds__(256) void fill_kernel(
    const int* __restrict__ dst, int* __restrict__ cursor, int* __restrict__ bucket)
{
    const int e = blockIdx.x * 256 + threadIdx.x;
    if (e < N_EDGES) {
        const int pos = atomicAdd(&cursor[dst[e]], 1);
        bucket[pos] = e;
    }
}

// One 64-lane wave per node; lane owns 2 columns (float2 = 8B/lane -> 512B/row).
// acc = x[node] + sum_e relu(x[src[e]] + ea[e]); single coalesced write.
__global__ __launch_bounds__(256) void gather_kernel(
    const float* __restrict__ x,
    const int*   __restrict__ srcIdx,
    const float* __restrict__ ea,
    const int*   __restrict__ offsets,
    const int*   __restrict__ bucket,
    float*       __restrict__ out)
{
    const int wave = threadIdx.x >> 6;
    const int lane = threadIdx.x & 63;
    const int node = blockIdx.x * 4 + wave;
    if (node >= N_NODES) return;
    const int c = lane * 2;

    const int p0 = offsets[node];
    const int p1 = offsets[node + 1];

    float2 acc = *reinterpret_cast<const float2*>(x + (i64)node * D + c);

    int p = p0;
    for (; p + 1 < p1; p += 2) {          // 2 edges/iter for ILP
        const int e0 = bucket[p], e1 = bucket[p + 1];
        const int s0 = srcIdx[e0], s1 = srcIdx[e1];
        const float2 xv0 = *reinterpret_cast<const float2*>(x  + (i64)s0 * D + c);
        const float2 ev0 = *reinterpret_cast<const float2*>(ea + (i64)e0 * D + c);
        const float2 xv1 = *reinterpret_cast<const float2*>(x  + (i64)s1 * D + c);
        const float2 ev1 = *reinterpret_cast<const float2*>(ea + (i64)e1 * D + c);
        acc.x += fmaxf(xv0.x + ev0.x, 0.f) + fmaxf(xv1.x + ev1.x, 0.f);
        acc.y += fmaxf(xv0.y + ev0.y, 0.f) + fmaxf(xv1.y + ev1.y, 0.f);
    }
    if (p < p1) {
        const int e0 = bucket[p];
        const int s0 = srcIdx[e0];
        const float2 xv0 = *reinterpret_cast<const float2*>(x  + (i64)s0 * D + c);
        const float2 ev0 = *reinterpret_cast<const float2*>(ea + (i64)e0 * D + c);
        acc.x += fmaxf(xv0.x + ev0.x, 0.f);
        acc.y += fmaxf(xv0.y + ev0.y, 0.f);
    }

    *reinterpret_cast<float2*>(out + (i64)node * D + c) = acc;
}

// ===========================================================================
// Fallback atomic path (proven correct in R2) — used only if ws too small
// ===========================================================================
__global__ __launch_bounds__(256) void init_acc_kernel(
    const float* __restrict__ x, float* __restrict__ acc)
{
    const int i = blockIdx.x * blockDim.x + threadIdx.x;
    const int n = N_NODES * D / 4;
    if (i < n)
        reinterpret_cast<float4*>(acc)[i] = reinterpret_cast<const float4*>(x)[i];
}

__global__ __launch_bounds__(256) void edge_scatter_kernel(
    const float* __restrict__ x,
    const int*  __restrict__ src,
    const int*  __restrict__ dst,
    const float* __restrict__ ea,
    float* __restrict__ acc)
{
    const int lane = threadIdx.x & 31;
    const int grp  = threadIdx.x >> 5;
    const i64 e = (i64)blockIdx.x * 8 + grp;
    if (e >= N_EDGES) return;
    const int s = src[e];
    const int d = dst[e];
    const int j = lane * 4;
    const float4 xv = *reinterpret_cast<const float4*>(x  + (i64)s * D + j);
    const float4 ev = *reinterpret_cast<const float4*>(ea + e * D + j);
    float4 m;
    m.x = fmaxf(xv.x + ev.x, 0.0f);
    m.y = fmaxf(xv.y + ev.y, 0.0f);
    m.z = fmaxf(xv.z + ev.z, 0.0f);
    m.w = fmaxf(xv.w + ev.w, 0.0f);
    float* pp = acc + (i64)d * D + j;
    atomicAdd(pp + 0, m.x);
    atomicAdd(pp + 1, m.y);
    atomicAdd(pp + 2, m.z);
    atomicAdd(pp + 3, m.w);
}

// ===========================================================================
// MLP layer (in-place safe, rows staged to LDS)
// ===========================================================================
#define MLP_THREADS 512
#define ROWS_PER_CHUNK 16
#define CHUNKS_PER_BLOCK 4
#define ROWS_PER_BLOCK (ROWS_PER_CHUNK * CHUNKS_PER_BLOCK)   // 64

template<bool RELU>
__global__ __launch_bounds__(MLP_THREADS) void mlp_layer_kernel(
    const float* __restrict__ hin,
    const float* __restrict__ w,
    const float* __restrict__ b,
    float* __restrict__ hout)
{
    __shared__ float ws_[D * D];
    __shared__ float bs_[D];
    __shared__ float hrow[ROWS_PER_CHUNK][D];

    const int tid = threadIdx.x;
    for (int t = tid; t < D * D / 4; t += MLP_THREADS)
        reinterpret_cast<float4*>(ws_)[t] = reinterpret_cast<const float4*>(w)[t];
    if (tid < D) bs_[tid] = b[tid];

    const int j = tid & (D - 1);
    const int q = tid >> 7;
    const int rowBase = blockIdx.x * ROWS_PER_BLOCK;

    for (int c = 0; c < CHUNKS_PER_BLOCK; ++c) {
        const int chunkRow = rowBase + c * ROWS_PER_CHUNK;
        __syncthreads();
        {
            const int r   = tid >> 5;
            const int col = (tid & 31) * 4;
            const int gi  = chunkRow + r;
            float4 v = make_float4(0.f, 0.f, 0.f, 0.f);
            if (gi < N_NODES)
                v = *reinterpret_cast<const float4*>(hin + (i64)gi * D + col);
            *reinterpret_cast<float4*>(&hrow[r][col]) = v;
        }
        __syncthreads();

        float acc0 = bs_[j], acc1 = bs_[j], acc2 = bs_[j], acc3 = bs_[j];
        const int r0 = q * 4;
        #pragma unroll 4
        for (int k = 0; k < D; ++k) {
            const float wv = ws_[k * D + j];
            acc0 = fmaf(hrow[r0 + 0][k], wv, acc0);
            acc1 = fmaf(hrow[r0 + 1][k], wv, acc1);
            acc2 = fmaf(hrow[r0 + 2][k], wv, acc2);
            acc3 = fmaf(hrow[r0 + 3][k], wv, acc3);
        }
        if (RELU) {
            acc0 = fmaxf(acc0, 0.f); acc1 = fmaxf(acc1, 0.f);
            acc2 = fmaxf(acc2, 0.f); acc3 = fmaxf(acc3, 0.f);
        }
        const int gi = chunkRow + r0;
        if (gi + 0 < N_NODES) hout[(i64)(gi + 0) * D + j] = acc0;
        if (gi + 1 < N_NODES) hout[(i64)(gi + 1) * D + j] = acc1;
        if (gi + 2 < N_NODES) hout[(i64)(gi + 2) * D + j] = acc2;
        if (gi + 3 < N_NODES) hout[(i64)(gi + 3) * D + j] = acc3;
    }
}

// ===========================================================================
extern "C" void kernel_launch(void* const* d_in, const int* in_sizes, int n_in,
                              void* d_out, int out_size, void* d_ws, size_t ws_size,
                              hipStream_t stream)
{
    const float* x  = (const float*)d_in[0];
    const int*   ei = (const int*)  d_in[1];   // [2, E] int32
    const float* ea = (const float*)d_in[2];
    const float* w1 = (const float*)d_in[3];
    const float* b1 = (const float*)d_in[4];
    const float* w2 = (const float*)d_in[5];
    const float* b2 = (const float*)d_in[6];
    float* out = (float*)d_out;

    const int* src = ei;
    const int* dst = ei + N_EDGES;

    // ws layout
    const size_t WS_INTS = (size_t)N_NODES + (N_NODES + 1) + N_NODES + 128 + N_EDGES;
    const size_t WS_NEEDED = WS_INTS * sizeof(int);

    if (ws_size >= WS_NEEDED) {
        int* counts    = (int*)d_ws;
        int* offsets   = counts + N_NODES;
        int* cursor    = offsets + (N_NODES + 1);
        int* blockSums = cursor + N_NODES;
        int* bucket    = blockSums + 128;

        count_zero_kernel<<<(N_NODES + 255) / 256, 256, 0, stream>>>(counts);
        hist_kernel<<<(N_EDGES + 255) / 256, 256, 0, stream>>>(dst, counts);
        scan_pass1<<<N_CHUNKS, SCAN_THREADS, 0, stream>>>(counts, blockSums);
        scan_pass2<<<1, 128, 0, stream>>>(blockSums, offsets);
        scan_pass3<<<N_CHUNKS, SCAN_THREADS, 0, stream>>>(counts, blockSums, offsets, cursor);
        fill_kernel<<<(N_EDGES + 255) / 256, 256, 0, stream>>>(dst, cursor, bucket);
        gather_kernel<<<(N_NODES + 3) / 4, 256, 0, stream>>>(x, src, ea, offsets, bucket, out);
    } else {
        // fallback: atomic scatter (R2 path)
        const int n = N_NODES * D / 4;
        init_acc_kernel<<<(n + 255) / 256, 256, 0, stream>>>(x, out);
        edge_scatter_kernel<<<(N_EDGES + 7) / 8, 256, 0, stream>>>(x, src, dst, ea, out);
    }

    const int blocks = (N_NODES + ROWS_PER_BLOCK - 1) / ROWS_PER_BLOCK;
    mlp_layer_kernel<true ><<<blocks, MLP_THREADS, 0, stream>>>(out, w1, b1, out);
    mlp_layer_kernel<false><<<blocks, MLP_THREADS, 0, stream>>>(out, w2, b2, out);
}

// Round 5
// 548.854 us; speedup vs baseline: 5.3444x; 1.2460x over previous
//
#include <hip/hip_runtime.h>
#include <stdint.h>

#define N_NODES 100000
#define N_EDGES 1600000
#define D 128
#define ROWS_PAD 100096   // 782 * 128

typedef long long i64;
typedef __attribute__((ext_vector_type(8))) short bf16x8;
typedef __attribute__((ext_vector_type(4))) float f32x4;

// f32 -> bf16 round-to-nearest-even (finite inputs)
__device__ __forceinline__ unsigned short f2bf(float f) {
    union { float f; unsigned u; } v; v.f = f;
    unsigned r = v.u + 0x7fff + ((v.u >> 16) & 1);
    return (unsigned short)(r >> 16);
}

// ===========================================================================
// CSR build (proven R2/R3 incl. post-timing)
// ===========================================================================
#define SCAN_CHUNK 1024
#define SCAN_THREADS 256
#define N_CHUNKS ((N_NODES + SCAN_CHUNK - 1) / SCAN_CHUNK)   // 98

__global__ __launch_bounds__(256) void count_zero_kernel(int* __restrict__ counts)
{
    const int i = blockIdx.x * 256 + threadIdx.x;
    if (i < N_NODES) counts[i] = 0;
}

__global__ __launch_bounds__(256) void hist_kernel(
    const int* __restrict__ dst, int* __restrict__ counts)
{
    const int e = blockIdx.x * 256 + threadIdx.x;
    if (e < N_EDGES) atomicAdd(&counts[dst[e]], 1);
}

__global__ __launch_bounds__(SCAN_THREADS) void scan_pass1(
    const int* __restrict__ counts, int* __restrict__ blockSums)
{
    __shared__ int sdata[SCAN_THREADS];
    const int b = blockIdx.x, t = threadIdx.x;
    const int base = b * SCAN_CHUNK + t * 4;
    int s = 0;
    #pragma unroll
    for (int k = 0; k < 4; ++k) {
        const int i = base + k;
        if (i < N_NODES) s += counts[i];
    }
    sdata[t] = s; __syncthreads();
    for (int off = SCAN_THREADS / 2; off > 0; off >>= 1) {
        if (t < off) sdata[t] += sdata[t + off];
        __syncthreads();
    }
    if (t == 0) blockSums[b] = sdata[0];
}

__global__ __launch_bounds__(128) void scan_pass2(
    int* __restrict__ blockSums, int* __restrict__ offsets)
{
    __shared__ int sh[128];
    const int t = threadIdx.x;
    const int v = (t < N_CHUNKS) ? blockSums[t] : 0;
    sh[t] = v; __syncthreads();
    for (int off = 1; off < 128; off <<= 1) {
        const int add = (t >= off) ? sh[t - off] : 0;
        __syncthreads();
        sh[t] += add;
        __syncthreads();
    }
    const int incl = sh[t];
    if (t < N_CHUNKS) blockSums[t] = incl - v;       // exclusive chunk base
    if (t == N_CHUNKS - 1) offsets[N_NODES] = incl;  // total = N_EDGES
}

__global__ __launch_bounds__(SCAN_THREADS) void scan_pass3(
    const int* __restrict__ counts, const int* __restrict__ blockSums,
    int* __restrict__ offsets, int* __restrict__ cursor)
{
    __shared__ int sh[SCAN_THREADS];
    const int b = blockIdx.x, t = threadIdx.x;
    const int base = b * SCAN_CHUNK + t * 4;
    int v[4]; int s = 0;
    #pragma unroll
    for (int k = 0; k < 4; ++k) {
        const int i = base + k;
        v[k] = (i < N_NODES) ? counts[i] : 0;
        s += v[k];
    }
    sh[t] = s; __syncthreads();
    for (int off = 1; off < SCAN_THREADS; off <<= 1) {
        const int add = (t >= off) ? sh[t - off] : 0;
        __syncthreads();
        sh[t] += add;
        __syncthreads();
    }
    int run = blockSums[b] + (sh[t] - s);
    #pragma unroll
    for (int k = 0; k < 4; ++k) {
        const int i = base + k;
        if (i < N_NODES) { offsets[i] = run; cursor[i] = run; }
        run += v[k];
    }
}

__global__ __launch_bounds__(256) void fill_kernel(
    const int* __restrict__ dst, int* __restrict__ cursor, int* __restrict__ bucket)
{
    const int e = blockIdx.x * 256 + threadIdx.x;
    if (e < N_EDGES) {
        const int pos = atomicAdd(&cursor[dst[e]], 1);
        bucket[pos] = e;
    }
}

// ===========================================================================
// Zero the pad rows of h0 (f32) and h1 (bf16) every call — no cell the MLP
// kernels can read is ever left holding harness poison.
// ===========================================================================
__global__ __launch_bounds__(256) void pad_zero_kernel(
    float* __restrict__ h0, unsigned short* __restrict__ h1)
{
    const int i = blockIdx.x * 256 + threadIdx.x;
    const int PADE = (ROWS_PAD - N_NODES) * D;     // 12288
    if (i < PADE) {
        h0[(i64)N_NODES * D + i] = 0.0f;
        h1[(i64)N_NODES * D + i] = 0;
    }
}

// ===========================================================================
// Gather: wave per node; lanes prefetch up to 64 edge ids, bitonic-sort them
// (canonical order -> bit-deterministic across replays regardless of fill's
// atomic permutation), then shfl-broadcast so x/ea loads pipeline.
// Output f32 (R3's proven intermediate format).
// ===========================================================================
__global__ __launch_bounds__(256) void gather_kernel(
    const float* __restrict__ x,
    const int*   __restrict__ srcIdx,
    const float* __restrict__ ea,
    const int*   __restrict__ offsets,
    const int*   __restrict__ bucket,
    float*       __restrict__ h0)
{
    const int wave = threadIdx.x >> 6;
    const int lane = threadIdx.x & 63;
    const int node = blockIdx.x * 4 + wave;
    if (node >= N_NODES) return;
    const int c = lane * 2;

    const int p0 = offsets[node];
    const int p1 = offsets[node + 1];

    float2 acc = *reinterpret_cast<const float2*>(x + (i64)node * D + c);

    for (int base = p0; base < p1; base += 64) {
        const int n = min(64, p1 - base);

        int key = 0x7fffffff;
        if (lane < n) key = bucket[base + lane];

        // 64-lane bitonic sort, ascending (INT_MAX pads sink to top lanes)
        #pragma unroll
        for (int k = 2; k <= 64; k <<= 1) {
            #pragma unroll
            for (int j = k >> 1; j > 0; j >>= 1) {
                const int other = __shfl_xor(key, j);
                const bool up    = ((lane & k) == 0);
                const bool lower = ((lane & j) == 0);
                key = (lower == up) ? min(key, other) : max(key, other);
            }
        }

        const int e = key;
        int s = 0;
        if (lane < n) s = srcIdx[e];

        int it = 0;
        for (; it + 3 < n; it += 4) {
            const int e0 = __shfl(e, it),     s0 = __shfl(s, it);
            const int e1 = __shfl(e, it + 1), s1 = __shfl(s, it + 1);
            const int e2 = __shfl(e, it + 2), s2 = __shfl(s, it + 2);
            const int e3 = __shfl(e, it + 3), s3 = __shfl(s, it + 3);
            const float2 xv0 = *reinterpret_cast<const float2*>(x  + (i64)s0 * D + c);
            const float2 ev0 = *reinterpret_cast<const float2*>(ea + (i64)e0 * D + c);
            const float2 xv1 = *reinterpret_cast<const float2*>(x  + (i64)s1 * D + c);
            const float2 ev1 = *reinterpret_cast<const float2*>(ea + (i64)e1 * D + c);
            const float2 xv2 = *reinterpret_cast<const float2*>(x  + (i64)s2 * D + c);
            const float2 ev2 = *reinterpret_cast<const float2*>(ea + (i64)e2 * D + c);
            const float2 xv3 = *reinterpret_cast<const float2*>(x  + (i64)s3 * D + c);
            const float2 ev3 = *reinterpret_cast<const float2*>(ea + (i64)e3 * D + c);
            acc.x += fmaxf(xv0.x + ev0.x, 0.f) + fmaxf(xv1.x + ev1.x, 0.f)
                   + fmaxf(xv2.x + ev2.x, 0.f) + fmaxf(xv3.x + ev3.x, 0.f);
            acc.y += fmaxf(xv0.y + ev0.y, 0.f) + fmaxf(xv1.y + ev1.y, 0.f)
                   + fmaxf(xv2.y + ev2.y, 0.f) + fmaxf(xv3.y + ev3.y, 0.f);
        }
        for (; it < n; ++it) {
            const int e0 = __shfl(e, it), s0 = __shfl(s, it);
            const float2 xv0 = *reinterpret_cast<const float2*>(x  + (i64)s0 * D + c);
            const float2 ev0 = *reinterpret_cast<const float2*>(ea + (i64)e0 * D + c);
            acc.x += fmaxf(xv0.x + ev0.x, 0.f);
            acc.y += fmaxf(xv0.y + ev0.y, 0.f);
        }
    }

    *reinterpret_cast<float2*>(h0 + (i64)node * D + c) = acc;
}

// ===========================================================================
// MFMA MLP layers. m92-verified 16x16x32 bf16 fragment maps:
//   A: row = lane&15, k = 8*(lane>>4)+j    (same k-map as B => consistent)
//   B: col = lane&15, k = 8*(lane>>4)+j
//   C: col = lane&15, row = (lane>>4)*4 + reg
// All ROWS_PAD rows processed unconditionally (pads zeroed).
// ===========================================================================
// Layer 1: f32 in -> relu -> bf16 out
__global__ __launch_bounds__(256) void mlp1_mfma_kernel(
    const float* __restrict__ hin,            // [ROWS_PAD][D] f32
    const float* __restrict__ w,              // [D][D] f32, w[k*D+col]
    const float* __restrict__ bias,           // [D]
    unsigned short* __restrict__ hout)        // [ROWS_PAD][D] bf16
{
    const int tid  = threadIdx.x;
    const int wave = tid >> 6;
    const int lane = tid & 63;
    const int g    = lane >> 4;
    const int lr   = lane & 15;
    const int colbase = wave * 32;

    bf16x8 bfrag[4][2];
    #pragma unroll
    for (int ks = 0; ks < 4; ++ks) {
        #pragma unroll
        for (int nt = 0; nt < 2; ++nt) {
            const int col = colbase + nt * 16 + lr;
            const int k0  = ks * 32 + g * 8;
            bf16x8 f;
            #pragma unroll
            for (int j = 0; j < 8; ++j)
                f[j] = (short)f2bf(w[(k0 + j) * D + col]);
            bfrag[ks][nt] = f;
        }
    }
    const float bc0 = bias[colbase + lr];
    const float bc1 = bias[colbase + 16 + lr];

    const int rowbase0 = blockIdx.x * 128;
    #pragma unroll 1
    for (int sub = 0; sub < 8; ++sub) {
        const int rowbase = rowbase0 + sub * 16;
        const int arow = rowbase + lr;

        bf16x8 afrag[4];
        #pragma unroll
        for (int ks = 0; ks < 4; ++ks) {
            const float* ap = hin + (i64)arow * D + ks * 32 + g * 8;
            const float4 u0 = *reinterpret_cast<const float4*>(ap);
            const float4 u1 = *reinterpret_cast<const float4*>(ap + 4);
            bf16x8 f;
            f[0] = (short)f2bf(u0.x); f[1] = (short)f2bf(u0.y);
            f[2] = (short)f2bf(u0.z); f[3] = (short)f2bf(u0.w);
            f[4] = (short)f2bf(u1.x); f[5] = (short)f2bf(u1.y);
            f[6] = (short)f2bf(u1.z); f[7] = (short)f2bf(u1.w);
            afrag[ks] = f;
        }

        f32x4 acc0 = { bc0, bc0, bc0, bc0 };
        f32x4 acc1 = { bc1, bc1, bc1, bc1 };
        #pragma unroll
        for (int ks = 0; ks < 4; ++ks) {
            acc0 = __builtin_amdgcn_mfma_f32_16x16x32_bf16(afrag[ks], bfrag[ks][0], acc0, 0, 0, 0);
            acc1 = __builtin_amdgcn_mfma_f32_16x16x32_bf16(afrag[ks], bfrag[ks][1], acc1, 0, 0, 0);
        }

        #pragma unroll
        for (int r = 0; r < 4; ++r) {
            const int orow = rowbase + g * 4 + r;
            hout[(i64)orow * D + colbase + lr]      = f2bf(fmaxf(acc0[r], 0.f));
            hout[(i64)orow * D + colbase + 16 + lr] = f2bf(fmaxf(acc1[r], 0.f));
        }
    }
}

// Layer 2: bf16 in -> f32 out (guarded store)
__global__ __launch_bounds__(256) void mlp2_mfma_kernel(
    const unsigned short* __restrict__ hin,   // [ROWS_PAD][D] bf16
    const float* __restrict__ w,
    const float* __restrict__ bias,
    float* __restrict__ hout)                 // [N_NODES][D] f32
{
    const int tid  = threadIdx.x;
    const int wave = tid >> 6;
    const int lane = tid & 63;
    const int g    = lane >> 4;
    const int lr   = lane & 15;
    const int colbase = wave * 32;

    bf16x8 bfrag[4][2];
    #pragma unroll
    for (int ks = 0; ks < 4; ++ks) {
        #pragma unroll
        for (int nt = 0; nt < 2; ++nt) {
            const int col = colbase + nt * 16 + lr;
            const int k0  = ks * 32 + g * 8;
            bf16x8 f;
            #pragma unroll
            for (int j = 0; j < 8; ++j)
                f[j] = (short)f2bf(w[(k0 + j) * D + col]);
            bfrag[ks][nt] = f;
        }
    }
    const float bc0 = bias[colbase + lr];
    const float bc1 = bias[colbase + 16 + lr];

    const int rowbase0 = blockIdx.x * 128;
    #pragma unroll 1
    for (int sub = 0; sub < 8; ++sub) {
        const int rowbase = rowbase0 + sub * 16;
        const int arow = rowbase + lr;

        bf16x8 afrag[4];
        #pragma unroll
        for (int ks = 0; ks < 4; ++ks)
            afrag[ks] = *reinterpret_cast<const bf16x8*>(
                hin + (i64)arow * D + ks * 32 + g * 8);

        f32x4 acc0 = { bc0, bc0, bc0, bc0 };
        f32x4 acc1 = { bc1, bc1, bc1, bc1 };
        #pragma unroll
        for (int ks = 0; ks < 4; ++ks) {
            acc0 = __builtin_amdgcn_mfma_f32_16x16x32_bf16(afrag[ks], bfrag[ks][0], acc0, 0, 0, 0);
            acc1 = __builtin_amdgcn_mfma_f32_16x16x32_bf16(afrag[ks], bfrag[ks][1], acc1, 0, 0, 0);
        }

        #pragma unroll
        for (int r = 0; r < 4; ++r) {
            const int orow = rowbase + g * 4 + r;
            if (orow < N_NODES) {
                hout[(i64)orow * D + colbase + lr]      = acc0[r];
                hout[(i64)orow * D + colbase + 16 + lr] = acc1[r];
            }
        }
    }
}

// ===========================================================================
// Fallback path (R2-proven) — only if ws too small
// ===========================================================================
__global__ __launch_bounds__(256) void init_acc_kernel(
    const float* __restrict__ x, float* __restrict__ acc)
{
    const int i = blockIdx.x * blockDim.x + threadIdx.x;
    const int n = N_NODES * D / 4;
    if (i < n)
        reinterpret_cast<float4*>(acc)[i] = reinterpret_cast<const float4*>(x)[i];
}

__global__ __launch_bounds__(256) void edge_scatter_kernel(
    const float* __restrict__ x,
    const int*  __restrict__ src,
    const int*  __restrict__ dst,
    const float* __restrict__ ea,
    float* __restrict__ acc)
{
    const int lane = threadIdx.x & 31;
    const int grp  = threadIdx.x >> 5;
    const i64 e = (i64)blockIdx.x * 8 + grp;
    if (e >= N_EDGES) return;
    const int s = src[e];
    const int d = dst[e];
    const int j = lane * 4;
    const float4 xv = *reinterpret_cast<const float4*>(x  + (i64)s * D + j);
    const float4 ev = *reinterpret_cast<const float4*>(ea + e * D + j);
    float4 m;
    m.x = fmaxf(xv.x + ev.x, 0.0f);
    m.y = fmaxf(xv.y + ev.y, 0.0f);
    m.z = fmaxf(xv.z + ev.z, 0.0f);
    m.w = fmaxf(xv.w + ev.w, 0.0f);
    float* pp = acc + (i64)d * D + j;
    atomicAdd(pp + 0, m.x);
    atomicAdd(pp + 1, m.y);
    atomicAdd(pp + 2, m.z);
    atomicAdd(pp + 3, m.w);
}

#define MLP_THREADS 512
#define ROWS_PER_CHUNK 16
#define CHUNKS_PER_BLOCK 4
#define ROWS_PER_BLOCK (ROWS_PER_CHUNK * CHUNKS_PER_BLOCK)

template<bool RELU>
__global__ __launch_bounds__(MLP_THREADS) void mlp_layer_kernel(
    const float* __restrict__ hin,
    const float* __restrict__ w,
    const float* __restrict__ b,
    float* __restrict__ hout)
{
    __shared__ float ws_[D * D];
    __shared__ float bs_[D];
    __shared__ float hrow[ROWS_PER_CHUNK][D];

    const int tid = threadIdx.x;
    for (int t = tid; t < D * D / 4; t += MLP_THREADS)
        reinterpret_cast<float4*>(ws_)[t] = reinterpret_cast<const float4*>(w)[t];
    if (tid < D) bs_[tid] = b[tid];

    const int j = tid & (D - 1);
    const int q = tid >> 7;
    const int rowBase = blockIdx.x * ROWS_PER_BLOCK;

    for (int c = 0; c < CHUNKS_PER_BLOCK; ++c) {
        const int chunkRow = rowBase + c * ROWS_PER_CHUNK;
        __syncthreads();
        {
            const int r   = tid >> 5;
            const int col = (tid & 31) * 4;
            const int gi  = chunkRow + r;
            float4 v = make_float4(0.f, 0.f, 0.f, 0.f);
            if (gi < N_NODES)
                v = *reinterpret_cast<const float4*>(hin + (i64)gi * D + col);
            *reinterpret_cast<float4*>(&hrow[r][col]) = v;
        }
        __syncthreads();

        float acc0 = bs_[j], acc1 = bs_[j], acc2 = bs_[j], acc3 = bs_[j];
        const int r0 = q * 4;
        #pragma unroll 4
        for (int k = 0; k < D; ++k) {
            const float wv = ws_[k * D + j];
            acc0 = fmaf(hrow[r0 + 0][k], wv, acc0);
            acc1 = fmaf(hrow[r0 + 1][k], wv, acc1);
            acc2 = fmaf(hrow[r0 + 2][k], wv, acc2);
            acc3 = fmaf(hrow[r0 + 3][k], wv, acc3);
        }
        if (RELU) {
            acc0 = fmaxf(acc0, 0.f); acc1 = fmaxf(acc1, 0.f);
            acc2 = fmaxf(acc2, 0.f); acc3 = fmaxf(acc3, 0.f);
        }
        const int gi = chunkRow + r0;
        if (gi + 0 < N_NODES) hout[(i64)(gi + 0) * D + j] = acc0;
        if (gi + 1 < N_NODES) hout[(i64)(gi + 1) * D + j] = acc1;
        if (gi + 2 < N_NODES) hout[(i64)(gi + 2) * D + j] = acc2;
        if (gi + 3 < N_NODES) hout[(i64)(gi + 3) * D + j] = acc3;
    }
}

// ===========================================================================
extern "C" void kernel_launch(void* const* d_in, const int* in_sizes, int n_in,
                              void* d_out, int out_size, void* d_ws, size_t ws_size,
                              hipStream_t stream)
{
    const float* x  = (const float*)d_in[0];
    const int*   ei = (const int*)  d_in[1];   // [2, E] int32
    const float* ea = (const float*)d_in[2];
    const float* w1 = (const float*)d_in[3];
    const float* b1 = (const float*)d_in[4];
    const float* w2 = (const float*)d_in[5];
    const float* b2 = (const float*)d_in[6];
    float* out = (float*)d_out;

    const int* src = ei;
    const int* dst = ei + N_EDGES;

    // ws layout: int region | h0 f32 [ROWS_PAD][D] | h1 bf16 [ROWS_PAD][D]
    const size_t INT_REGION = (size_t)N_NODES + (N_NODES + 1) + N_NODES + 128 + N_EDGES;
    const size_t H_ELEMS    = (size_t)ROWS_PAD * D;
    const size_t WS_NEEDED  = INT_REGION * 4 + 32 + H_ELEMS * 4 + H_ELEMS * 2;

    if (ws_size >= WS_NEEDED) {
        int* counts    = (int*)d_ws;
        int* offsets   = counts + N_NODES;
        int* cursor    = offsets + (N_NODES + 1);
        int* blockSums = cursor + N_NODES;
        int* bucket    = blockSums + 128;
        uintptr_t p = (uintptr_t)(bucket + N_EDGES);
        p = (p + 15) & ~(uintptr_t)15;
        float* h0 = (float*)p;
        unsigned short* h1 = (unsigned short*)(h0 + H_ELEMS);

        count_zero_kernel<<<(N_NODES + 255) / 256, 256, 0, stream>>>(counts);
        hist_kernel<<<(N_EDGES + 255) / 256, 256, 0, stream>>>(dst, counts);
        scan_pass1<<<N_CHUNKS, SCAN_THREADS, 0, stream>>>(counts, blockSums);
        scan_pass2<<<1, 128, 0, stream>>>(blockSums, offsets);
        scan_pass3<<<N_CHUNKS, SCAN_THREADS, 0, stream>>>(counts, blockSums, offsets, cursor);
        fill_kernel<<<(N_EDGES + 255) / 256, 256, 0, stream>>>(dst, cursor, bucket);
        pad_zero_kernel<<<48, 256, 0, stream>>>(h0, h1);
        gather_kernel<<<(N_NODES + 3) / 4, 256, 0, stream>>>(x, src, ea, offsets, bucket, h0);

        const int mlpBlocks = ROWS_PAD / 128;   // 782
        mlp1_mfma_kernel<<<mlpBlocks, 256, 0, stream>>>(h0, w1, b1, h1);
        mlp2_mfma_kernel<<<mlpBlocks, 256, 0, stream>>>(h1, w2, b2, out);
    } else {
        const int n = N_NODES * D / 4;
        init_acc_kernel<<<(n + 255) / 256, 256, 0, stream>>>(x, out);
        edge_scatter_kernel<<<(N_EDGES + 7) / 8, 256, 0, stream>>>(x, src, dst, ea, out);
        const int blocks = (N_NODES + ROWS_PER_BLOCK - 1) / ROWS_PER_BLOCK;
        mlp_layer_kernel<true ><<<blocks, MLP_THREADS, 0, stream>>>(out, w1, b1, out);
        mlp_layer_kernel<false><<<blocks, MLP_THREADS, 0, stream>>>(out, w2, b2, out);
    }
}

// Round 7
// 545.249 us; speedup vs baseline: 5.3797x; 1.0066x over previous
//
#include <hip/hip_runtime.h>
#include <stdint.h>

#define N_NODES 100000
#define N_EDGES 1600000
#define D 128
#define ROWS_PAD 100096   // 782 * 128

typedef long long i64;
typedef __attribute__((ext_vector_type(8))) short bf16x8;
typedef __attribute__((ext_vector_type(4))) float f32x4;
typedef __attribute__((ext_vector_type(4))) float fv4;   // native vec for nontemporal builtins

// f32 -> bf16 round-to-nearest-even (finite inputs)
__device__ __forceinline__ unsigned short f2bf(float f) {
    union { float f; unsigned u; } v; v.f = f;
    unsigned r = v.u + 0x7fff + ((v.u >> 16) & 1);
    return (unsigned short)(r >> 16);
}

// ===========================================================================
// CSR build (proven R2..R5)
// ===========================================================================
#define SCAN_CHUNK 1024
#define SCAN_THREADS 256
#define N_CHUNKS ((N_NODES + SCAN_CHUNK - 1) / SCAN_CHUNK)   // 98

__global__ __launch_bounds__(256) void count_zero_kernel(int* __restrict__ counts)
{
    const int i = blockIdx.x * 256 + threadIdx.x;
    if (i < N_NODES) counts[i] = 0;
}

__global__ __launch_bounds__(256) void hist_kernel(
    const int* __restrict__ dst, int* __restrict__ counts)
{
    const int e = blockIdx.x * 256 + threadIdx.x;
    if (e < N_EDGES) atomicAdd(&counts[dst[e]], 1);
}

__global__ __launch_bounds__(SCAN_THREADS) void scan_pass1(
    const int* __restrict__ counts, int* __restrict__ blockSums)
{
    __shared__ int sdata[SCAN_THREADS];
    const int b = blockIdx.x, t = threadIdx.x;
    const int base = b * SCAN_CHUNK + t * 4;
    int s = 0;
    #pragma unroll
    for (int k = 0; k < 4; ++k) {
        const int i = base + k;
        if (i < N_NODES) s += counts[i];
    }
    sdata[t] = s; __syncthreads();
    for (int off = SCAN_THREADS / 2; off > 0; off >>= 1) {
        if (t < off) sdata[t] += sdata[t + off];
        __syncthreads();
    }
    if (t == 0) blockSums[b] = sdata[0];
}

__global__ __launch_bounds__(128) void scan_pass2(
    int* __restrict__ blockSums, int* __restrict__ offsets)
{
    __shared__ int sh[128];
    const int t = threadIdx.x;
    const int v = (t < N_CHUNKS) ? blockSums[t] : 0;
    sh[t] = v; __syncthreads();
    for (int off = 1; off < 128; off <<= 1) {
        const int add = (t >= off) ? sh[t - off] : 0;
        __syncthreads();
        sh[t] += add;
        __syncthreads();
    }
    const int incl = sh[t];
    if (t < N_CHUNKS) blockSums[t] = incl - v;       // exclusive chunk base
    if (t == N_CHUNKS - 1) offsets[N_NODES] = incl;  // total = N_EDGES
}

__global__ __launch_bounds__(SCAN_THREADS) void scan_pass3(
    const int* __restrict__ counts, const int* __restrict__ blockSums,
    int* __restrict__ offsets, int* __restrict__ cursor)
{
    __shared__ int sh[SCAN_THREADS];
    const int b = blockIdx.x, t = threadIdx.x;
    const int base = b * SCAN_CHUNK + t * 4;
    int v[4]; int s = 0;
    #pragma unroll
    for (int k = 0; k < 4; ++k) {
        const int i = base + k;
        v[k] = (i < N_NODES) ? counts[i] : 0;
        s += v[k];
    }
    sh[t] = s; __syncthreads();
    for (int off = 1; off < SCAN_THREADS; off <<= 1) {
        const int add = (t >= off) ? sh[t - off] : 0;
        __syncthreads();
        sh[t] += add;
        __syncthreads();
    }
    int run = blockSums[b] + (sh[t] - s);
    #pragma unroll
    for (int k = 0; k < 4; ++k) {
        const int i = base + k;
        if (i < N_NODES) { offsets[i] = run; cursor[i] = run; }
        run += v[k];
    }
}

__global__ __launch_bounds__(256) void fill_kernel(
    const int* __restrict__ dst, int* __restrict__ cursor, int* __restrict__ bucket)
{
    const int e = blockIdx.x * 256 + threadIdx.x;
    if (e < N_EDGES) {
        const int pos = atomicAdd(&cursor[dst[e]], 1);
        bucket[pos] = e;
    }
}

// ===========================================================================
// Zero pad rows of h0 (f32) and h1 (bf16) every call.
// ===========================================================================
__global__ __launch_bounds__(256) void pad_zero_kernel(
    float* __restrict__ h0, unsigned short* __restrict__ h1)
{
    const int i = blockIdx.x * 256 + threadIdx.x;
    const int PADE = (ROWS_PAD - N_NODES) * D;     // 12288
    if (i < PADE) {
        h0[(i64)N_NODES * D + i] = 0.0f;
        h1[(i64)N_NODES * D + i] = 0;
    }
}

// ===========================================================================
// Gather v3: wave per node, HALF-WAVE per edge (lane = 4 cols).
// Each wave-instruction moves 2 edges x 512B = 1KB; 4 pairs unrolled = 8KB
// in flight per wave. Bitonic sort keeps accumulation order canonical
// (bit-deterministic across replays). Nontemporal ea loads keep L2 for x.
// ===========================================================================
#define PAIR(p) {                                                               \
    const int idx = 2*(p) + half;                                               \
    const bool v = idx < n;                                                     \
    int e_ = __shfl(key, idx);                                                  \
    int s_ = __shfl(sk, idx);                                                   \
    e_ = v ? e_ : 0; s_ = v ? s_ : 0;                                           \
    const fv4 xv = *reinterpret_cast<const fv4*>(x + (i64)s_ * D + c4);         \
    const fv4 ev = __builtin_nontemporal_load(                                  \
        reinterpret_cast<const fv4*>(ea + (i64)e_ * D + c4));                   \
    if (v) {                                                                    \
        acc.x += fmaxf(xv.x + ev.x, 0.f);                                       \
        acc.y += fmaxf(xv.y + ev.y, 0.f);                                       \
        acc.z += fmaxf(xv.z + ev.z, 0.f);                                       \
        acc.w += fmaxf(xv.w + ev.w, 0.f);                                       \
    }                                                                           \
}

__global__ __launch_bounds__(256) void gather_kernel(
    const float* __restrict__ x,
    const int*   __restrict__ srcIdx,
    const float* __restrict__ ea,
    const int*   __restrict__ offsets,
    const int*   __restrict__ bucket,
    float*       __restrict__ h0)
{
    const int wave = threadIdx.x >> 6;
    const int lane = threadIdx.x & 63;
    const int node = blockIdx.x * 4 + wave;
    if (node >= N_NODES) return;
    const int half = lane >> 5;            // 0: even slots, 1: odd slots
    const int c4   = (lane & 31) * 4;      // 4 cols per lane

    const int p0 = offsets[node];
    const int p1 = offsets[node + 1];

    fv4 acc;
    if (half == 0) acc = *reinterpret_cast<const fv4*>(x + (i64)node * D + c4);
    else           acc = (fv4){0.f, 0.f, 0.f, 0.f};

    for (int base = p0; base < p1; base += 64) {
        const int n = min(64, p1 - base);

        int key = 0x7fffffff;
        if (lane < n) key = bucket[base + lane];

        // 64-lane bitonic sort, ascending (INT_MAX pads sink to top lanes)
        #pragma unroll
        for (int k = 2; k <= 64; k <<= 1) {
            #pragma unroll
            for (int j = k >> 1; j > 0; j >>= 1) {
                const int other = __shfl_xor(key, j);
                const bool up    = ((lane & k) == 0);
                const bool lower = ((lane & j) == 0);
                key = (lower == up) ? min(key, other) : max(key, other);
            }
        }

        int sk = 0;
        if (lane < n) sk = srcIdx[key];

        const int npair = (n + 1) >> 1;
        int it = 0;
        for (; it + 3 < npair; it += 4) {
            PAIR(it) PAIR(it + 1) PAIR(it + 2) PAIR(it + 3)
        }
        for (; it < npair; ++it) { PAIR(it) }
    }

    // combine halves: commutative add -> identical in both lanes, deterministic
    acc.x += __shfl_xor(acc.x, 32);
    acc.y += __shfl_xor(acc.y, 32);
    acc.z += __shfl_xor(acc.z, 32);
    acc.w += __shfl_xor(acc.w, 32);

    if (half == 0)
        __builtin_nontemporal_store(acc,
            reinterpret_cast<fv4*>(h0 + (i64)node * D + c4));
}

// ===========================================================================
// MFMA MLP layers (unchanged from R5, proven). 16x16x32 bf16 maps:
//   A: row = lane&15, k = 8*(lane>>4)+j ; B: col = lane&15, same k-map
//   C: col = lane&15, row = (lane>>4)*4 + reg
// ===========================================================================
__global__ __launch_bounds__(256) void mlp1_mfma_kernel(
    const float* __restrict__ hin,            // [ROWS_PAD][D] f32
    const float* __restrict__ w,              // [D][D] f32, w[k*D+col]
    const float* __restrict__ bias,           // [D]
    unsigned short* __restrict__ hout)        // [ROWS_PAD][D] bf16
{
    const int tid  = threadIdx.x;
    const int wave = tid >> 6;
    const int lane = tid & 63;
    const int g    = lane >> 4;
    const int lr   = lane & 15;
    const int colbase = wave * 32;

    bf16x8 bfrag[4][2];
    #pragma unroll
    for (int ks = 0; ks < 4; ++ks) {
        #pragma unroll
        for (int nt = 0; nt < 2; ++nt) {
            const int col = colbase + nt * 16 + lr;
            const int k0  = ks * 32 + g * 8;
            bf16x8 f;
            #pragma unroll
            for (int j = 0; j < 8; ++j)
                f[j] = (short)f2bf(w[(k0 + j) * D + col]);
            bfrag[ks][nt] = f;
        }
    }
    const float bc0 = bias[colbase + lr];
    const float bc1 = bias[colbase + 16 + lr];

    const int rowbase0 = blockIdx.x * 128;
    #pragma unroll 1
    for (int sub = 0; sub < 8; ++sub) {
        const int rowbase = rowbase0 + sub * 16;
        const int arow = rowbase + lr;

        bf16x8 afrag[4];
        #pragma unroll
        for (int ks = 0; ks < 4; ++ks) {
            const float* ap = hin + (i64)arow * D + ks * 32 + g * 8;
            const float4 u0 = *reinterpret_cast<const float4*>(ap);
            const float4 u1 = *reinterpret_cast<const float4*>(ap + 4);
            bf16x8 f;
            f[0] = (short)f2bf(u0.x); f[1] = (short)f2bf(u0.y);
            f[2] = (short)f2bf(u0.z); f[3] = (short)f2bf(u0.w);
            f[4] = (short)f2bf(u1.x); f[5] = (short)f2bf(u1.y);
            f[6] = (short)f2bf(u1.z); f[7] = (short)f2bf(u1.w);
            afrag[ks] = f;
        }

        f32x4 acc0 = { bc0, bc0, bc0, bc0 };
        f32x4 acc1 = { bc1, bc1, bc1, bc1 };
        #pragma unroll
        for (int ks = 0; ks < 4; ++ks) {
            acc0 = __builtin_amdgcn_mfma_f32_16x16x32_bf16(afrag[ks], bfrag[ks][0], acc0, 0, 0, 0);
            acc1 = __builtin_amdgcn_mfma_f32_16x16x32_bf16(afrag[ks], bfrag[ks][1], acc1, 0, 0, 0);
        }

        #pragma unroll
        for (int r = 0; r < 4; ++r) {
            const int orow = rowbase + g * 4 + r;
            hout[(i64)orow * D + colbase + lr]      = f2bf(fmaxf(acc0[r], 0.f));
            hout[(i64)orow * D + colbase + 16 + lr] = f2bf(fmaxf(acc1[r], 0.f));
        }
    }
}

__global__ __launch_bounds__(256) void mlp2_mfma_kernel(
    const unsigned short* __restrict__ hin,   // [ROWS_PAD][D] bf16
    const float* __restrict__ w,
    const float* __restrict__ bias,
    float* __restrict__ hout)                 // [N_NODES][D] f32
{
    const int tid  = threadIdx.x;
    const int wave = tid >> 6;
    const int lane = tid & 63;
    const int g    = lane >> 4;
    const int lr   = lane & 15;
    const int colbase = wave * 32;

    bf16x8 bfrag[4][2];
    #pragma unroll
    for (int ks = 0; ks < 4; ++ks) {
        #pragma unroll
        for (int nt = 0; nt < 2; ++nt) {
            const int col = colbase + nt * 16 + lr;
            const int k0  = ks * 32 + g * 8;
            bf16x8 f;
            #pragma unroll
            for (int j = 0; j < 8; ++j)
                f[j] = (short)f2bf(w[(k0 + j) * D + col]);
            bfrag[ks][nt] = f;
        }
    }
    const float bc0 = bias[colbase + lr];
    const float bc1 = bias[colbase + 16 + lr];

    const int rowbase0 = blockIdx.x * 128;
    #pragma unroll 1
    for (int sub = 0; sub < 8; ++sub) {
        const int rowbase = rowbase0 + sub * 16;
        const int arow = rowbase + lr;

        bf16x8 afrag[4];
        #pragma unroll
        for (int ks = 0; ks < 4; ++ks)
            afrag[ks] = *reinterpret_cast<const bf16x8*>(
                hin + (i64)arow * D + ks * 32 + g * 8);

        f32x4 acc0 = { bc0, bc0, bc0, bc0 };
        f32x4 acc1 = { bc1, bc1, bc1, bc1 };
        #pragma unroll
        for (int ks = 0; ks < 4; ++ks) {
            acc0 = __builtin_amdgcn_mfma_f32_16x16x32_bf16(afrag[ks], bfrag[ks][0], acc0, 0, 0, 0);
            acc1 = __builtin_amdgcn_mfma_f32_16x16x32_bf16(afrag[ks], bfrag[ks][1], acc1, 0, 0, 0);
        }

        #pragma unroll
        for (int r = 0; r < 4; ++r) {
            const int orow = rowbase + g * 4 + r;
            if (orow < N_NODES) {
                hout[(i64)orow * D + colbase + lr]      = acc0[r];
                hout[(i64)orow * D + colbase + 16 + lr] = acc1[r];
            }
        }
    }
}

// ===========================================================================
// Fallback path (R2-proven) — only if ws too small
// ===========================================================================
__global__ __launch_bounds__(256) void init_acc_kernel(
    const float* __restrict__ x, float* __restrict__ acc)
{
    const int i = blockIdx.x * blockDim.x + threadIdx.x;
    const int n = N_NODES * D / 4;
    if (i < n)
        reinterpret_cast<float4*>(acc)[i] = reinterpret_cast<const float4*>(x)[i];
}

__global__ __launch_bounds__(256) void edge_scatter_kernel(
    const float* __restrict__ x,
    const int*  __restrict__ src,
    const int*  __restrict__ dst,
    const float* __restrict__ ea,
    float* __restrict__ acc)
{
    const int lane = threadIdx.x & 31;
    const int grp  = threadIdx.x >> 5;
    const i64 e = (i64)blockIdx.x * 8 + grp;
    if (e >= N_EDGES) return;
    const int s = src[e];
    const int d = dst[e];
    const int j = lane * 4;
    const float4 xv = *reinterpret_cast<const float4*>(x  + (i64)s * D + j);
    const float4 ev = *reinterpret_cast<const float4*>(ea + e * D + j);
    float4 m;
    m.x = fmaxf(xv.x + ev.x, 0.0f);
    m.y = fmaxf(xv.y + ev.y, 0.0f);
    m.z = fmaxf(xv.z + ev.z, 0.0f);
    m.w = fmaxf(xv.w + ev.w, 0.0f);
    float* pp = acc + (i64)d * D + j;
    atomicAdd(pp + 0, m.x);
    atomicAdd(pp + 1, m.y);
    atomicAdd(pp + 2, m.z);
    atomicAdd(pp + 3, m.w);
}

#define MLP_THREADS 512
#define ROWS_PER_CHUNK 16
#define CHUNKS_PER_BLOCK 4
#define ROWS_PER_BLOCK (ROWS_PER_CHUNK * CHUNKS_PER_BLOCK)

template<bool RELU>
__global__ __launch_bounds__(MLP_THREADS) void mlp_layer_kernel(
    const float* __restrict__ hin,
    const float* __restrict__ w,
    const float* __restrict__ b,
    float* __restrict__ hout)
{
    __shared__ float ws_[D * D];
    __shared__ float bs_[D];
    __shared__ float hrow[ROWS_PER_CHUNK][D];

    const int tid = threadIdx.x;
    for (int t = tid; t < D * D / 4; t += MLP_THREADS)
        reinterpret_cast<float4*>(ws_)[t] = reinterpret_cast<const float4*>(w)[t];
    if (tid < D) bs_[tid] = b[tid];

    const int j = tid & (D - 1);
    const int q = tid >> 7;
    const int rowBase = blockIdx.x * ROWS_PER_BLOCK;

    for (int c = 0; c < CHUNKS_PER_BLOCK; ++c) {
        const int chunkRow = rowBase + c * ROWS_PER_CHUNK;
        __syncthreads();
        {
            const int r   = tid >> 5;
            const int col = (tid & 31) * 4;
            const int gi  = chunkRow + r;
            float4 v = make_float4(0.f, 0.f, 0.f, 0.f);
            if (gi < N_NODES)
                v = *reinterpret_cast<const float4*>(hin + (i64)gi * D + col);
            *reinterpret_cast<float4*>(&hrow[r][col]) = v;
        }
        __syncthreads();

        float acc0 = bs_[j], acc1 = bs_[j], acc2 = bs_[j], acc3 = bs_[j];
        const int r0 = q * 4;
        #pragma unroll 4
        for (int k = 0; k < D; ++k) {
            const float wv = ws_[k * D + j];
            acc0 = fmaf(hrow[r0 + 0][k], wv, acc0);
            acc1 = fmaf(hrow[r0 + 1][k], wv, acc1);
            acc2 = fmaf(hrow[r0 + 2][k], wv, acc2);
            acc3 = fmaf(hrow[r0 + 3][k], wv, acc3);
        }
        if (RELU) {
            acc0 = fmaxf(acc0, 0.f); acc1 = fmaxf(acc1, 0.f);
            acc2 = fmaxf(acc2, 0.f); acc3 = fmaxf(acc3, 0.f);
        }
        const int gi = chunkRow + r0;
        if (gi + 0 < N_NODES) hout[(i64)(gi + 0) * D + j] = acc0;
        if (gi + 1 < N_NODES) hout[(i64)(gi + 1) * D + j] = acc1;
        if (gi + 2 < N_NODES) hout[(i64)(gi + 2) * D + j] = acc2;
        if (gi + 3 < N_NODES) hout[(i64)(gi + 3) * D + j] = acc3;
    }
}

// ===========================================================================
extern "C" void kernel_launch(void* const* d_in, const int* in_sizes, int n_in,
                              void* d_out, int out_size, void* d_ws, size_t ws_size,
                              hipStream_t stream)
{
    const float* x  = (const float*)d_in[0];
    const int*   ei = (const int*)  d_in[1];   // [2, E] int32
    const float* ea = (const float*)d_in[2];
    const float* w1 = (const float*)d_in[3];
    const float* b1 = (const float*)d_in[4];
    const float* w2 = (const float*)d_in[5];
    const float* b2 = (const float*)d_in[6];
    float* out = (float*)d_out;

    const int* src = ei;
    const int* dst = ei + N_EDGES;

    // ws layout: int region | h0 f32 [ROWS_PAD][D] | h1 bf16 [ROWS_PAD][D]
    const size_t INT_REGION = (size_t)N_NODES + (N_NODES + 1) + N_NODES + 128 + N_EDGES;
    const size_t H_ELEMS    = (size_t)ROWS_PAD * D;
    const size_t WS_NEEDED  = INT_REGION * 4 + 32 + H_ELEMS * 4 + H_ELEMS * 2;

    if (ws_size >= WS_NEEDED) {
        int* counts    = (int*)d_ws;
        int* offsets   = counts + N_NODES;
        int* cursor    = offsets + (N_NODES + 1);
        int* blockSums = cursor + N_NODES;
        int* bucket    = blockSums + 128;
        uintptr_t p = (uintptr_t)(bucket + N_EDGES);
        p = (p + 15) & ~(uintptr_t)15;
        float* h0 = (float*)p;
        unsigned short* h1 = (unsigned short*)(h0 + H_ELEMS);

        count_zero_kernel<<<(N_NODES + 255) / 256, 256, 0, stream>>>(counts);
        hist_kernel<<<(N_EDGES + 255) / 256, 256, 0, stream>>>(dst, counts);
        scan_pass1<<<N_CHUNKS, SCAN_THREADS, 0, stream>>>(counts, blockSums);
        scan_pass2<<<1, 128, 0, stream>>>(blockSums, offsets);
        scan_pass3<<<N_CHUNKS, SCAN_THREADS, 0, stream>>>(counts, blockSums, offsets, cursor);
        fill_kernel<<<(N_EDGES + 255) / 256, 256, 0, stream>>>(dst, cursor, bucket);
        pad_zero_kernel<<<48, 256, 0, stream>>>(h0, h1);
        gather_kernel<<<(N_NODES + 3) / 4, 256, 0, stream>>>(x, src, ea, offsets, bucket, h0);

        const int mlpBlocks = ROWS_PAD / 128;   // 782
        mlp1_mfma_kernel<<<mlpBlocks, 256, 0, stream>>>(h0, w1, b1, h1);
        mlp2_mfma_kernel<<<mlpBlocks, 256, 0, stream>>>(h1, w2, b2, out);
    } else {
        const int n = N_NODES * D / 4;
        init_acc_kernel<<<(n + 255) / 256, 256, 0, stream>>>(x, out);
        edge_scatter_kernel<<<(N_EDGES + 7) / 8, 256, 0, stream>>>(x, src, dst, ea, out);
        const int blocks = (N_NODES + ROWS_PER_BLOCK - 1) / ROWS_PER_BLOCK;
        mlp_layer_kernel<true ><<<blocks, MLP_THREADS, 0, stream>>>(out, w1, b1, out);
        mlp_layer_kernel<false><<<blocks, MLP_THREADS, 0, stream>>>(out, w2, b2, out);
    }
}